// Round 8
// baseline (247.331 us; speedup 1.0000x reference)
//
#include <hip/hip_runtime.h>

#define N_NODES 50000
#define N_EDGES 800000
#define CAP 64

typedef unsigned int uint32;
typedef unsigned short u16;

typedef __attribute__((ext_vector_type(8))) short bf16x8;
typedef __attribute__((ext_vector_type(4))) float f32x4;

__device__ __forceinline__ uint32 f32_to_bf16_rne(float f) {
    uint32 u = __float_as_uint(f);
    u += 0x7fffu + ((u >> 16) & 1u);
    return u >> 16;
}
__device__ __forceinline__ float bf16lo_to_f32(uint32 v) { return __uint_as_float(v << 16); }
__device__ __forceinline__ float bf16hi_to_f32(uint32 v) { return __uint_as_float(v & 0xffff0000u); }

// ---------------- prep: zero cursor + W -> WT bf16 tables (one launch) ----------------
__global__ __launch_bounds__(256) void prep_kernel(const float* __restrict__ W1,
                                                   const float* __restrict__ W2,
                                                   const float* __restrict__ W3,
                                                   uint32* __restrict__ wt1,
                                                   uint32* __restrict__ wt2,
                                                   uint32* __restrict__ wt3,
                                                   int* __restrict__ cursor) {
    int b = blockIdx.x, tid = threadIdx.x;
    if (b < 196) {
        int i = b * 256 + tid;
        if (i < N_NODES) cursor[i] = 0;
        return;
    }
    b -= 196;
    const float* W;
    uint32* WT;
    int N;
    if (b < 32) { W = W1; WT = wt1; N = 128; }
    else if (b < 64) { W = W2; WT = wt2; N = 128; b -= 32; }
    else { W = W3; WT = wt3; N = 64; b -= 64; }
    int i = b * 256 + tid;
    if (i >= N * 64) return;
    int n = i >> 6, p = i & 63;
    WT[n * 64 + p] = f32_to_bf16_rne(W[(2 * p) * N + n]) |
                     (f32_to_bf16_rne(W[(2 * p + 1) * N + n]) << 16);
}

// ---------------- MFMA epilogue helper: pack bf16 col-pairs, store ----------------
__device__ __forceinline__ void pack_store(uint32* __restrict__ Cb, int rowstride_u,
                                           int row, int col, int r16, float v) {
    float nb = __shfl_xor(v, 1);
    if ((r16 & 1) == 0) {
        uint32 p = f32_to_bf16_rne(v) | (f32_to_bf16_rne(nb) << 16);
        Cb[(size_t)row * rowstride_u + (col >> 1)] = p;
    }
}

// ---------------- gemm1 body: A f32 global, converted in-register (64-row blocks) ----
__device__ __forceinline__ void gemm1_body(const float* __restrict__ A,
                                           const uint32* __restrict__ WTb,
                                           uint32* __restrict__ Cb, int M, int bid) {
    constexpr int NT = 2;
    const int tid = threadIdx.x;
    const int wave = tid >> 6;
    const int lane = tid & 63;
    const int r16 = lane & 15;
    const int g = lane >> 4;
    const int row0 = bid * 64;

    const float4* A4 = reinterpret_cast<const float4*>(A);
    const uint4* B4 = reinterpret_cast<const uint4*>(WTb);

    f32x4 acc[4][NT];
#pragma unroll
    for (int m = 0; m < 4; m++)
#pragma unroll
        for (int nt = 0; nt < NT; nt++) acc[m][nt] = (f32x4){0.f, 0.f, 0.f, 0.f};

    int rowm[4];
#pragma unroll
    for (int m = 0; m < 4; m++) {
        int r = row0 + m * 16 + r16;
        rowm[m] = r < M ? r : M - 1;
    }
    union U { uint4 u; bf16x8 v; };
#pragma unroll
    for (int kt = 0; kt < 4; kt++) {
        U b[NT];
#pragma unroll
        for (int nt = 0; nt < NT; nt++)
            b[nt].u = B4[(size_t)(nt * 64 + wave * 16 + r16) * 16 + kt * 4 + g];
        U a[4];
#pragma unroll
        for (int m = 0; m < 4; m++) {
            float4 f0 = A4[(size_t)rowm[m] * 32 + kt * 8 + g * 2];
            float4 f1 = A4[(size_t)rowm[m] * 32 + kt * 8 + g * 2 + 1];
            a[m].u.x = f32_to_bf16_rne(f0.x) | (f32_to_bf16_rne(f0.y) << 16);
            a[m].u.y = f32_to_bf16_rne(f0.z) | (f32_to_bf16_rne(f0.w) << 16);
            a[m].u.z = f32_to_bf16_rne(f1.x) | (f32_to_bf16_rne(f1.y) << 16);
            a[m].u.w = f32_to_bf16_rne(f1.z) | (f32_to_bf16_rne(f1.w) << 16);
        }
#pragma unroll
        for (int m = 0; m < 4; m++)
#pragma unroll
            for (int nt = 0; nt < NT; nt++)
                acc[m][nt] = __builtin_amdgcn_mfma_f32_16x16x32_bf16(a[m].v, b[nt].v, acc[m][nt], 0, 0, 0);
    }
#pragma unroll
    for (int m = 0; m < 4; m++)
#pragma unroll
        for (int nt = 0; nt < NT; nt++)
#pragma unroll
            for (int r = 0; r < 4; r++) {
                int row = row0 + m * 16 + g * 4 + r;
                if (row < M)
                    pack_store(Cb, 64, row, nt * 64 + wave * 16 + r16, r16, acc[m][nt][r]);
            }
}

// ---------------- fused build (line-partitioned) + gemm1 ----------------
#define EPT 8
#define EPB (256 * EPT)
#define GEMM1_BLOCKS 782   // ceil(50000/64)
#define BUILD_CHUNKS 391   // ceil(800000/2048)

__global__ __launch_bounds__(256) void build_gemm1_kernel(const float* __restrict__ x,
                                                          const uint32* __restrict__ wt1,
                                                          uint32* __restrict__ hwb,
                                                          const int* __restrict__ ei,
                                                          int* __restrict__ cursor,
                                                          u16* __restrict__ adj) {
    if (blockIdx.x < GEMM1_BLOCKS) {
        gemm1_body(x, wt1, hwb, N_NODES, blockIdx.x);
        return;
    }
    const int bb = blockIdx.x - GEMM1_BLOCKS;
    const int part = bb & 7;
    const int chunk = bb >> 3;
    const int base = chunk * EPB + threadIdx.x * EPT;
#pragma unroll
    for (int i = 0; i < EPT; i += 4) {
        int e = base + i;
        if (e + 3 < N_EDGES) {
            int4 s4 = *reinterpret_cast<const int4*>(&ei[e]);
            int4 d4 = *reinterpret_cast<const int4*>(&ei[N_EDGES + e]);
            int ss[4] = {s4.x, s4.y, s4.z, s4.w};
            int dd[4] = {d4.x, d4.y, d4.z, d4.w};
#pragma unroll
            for (int j = 0; j < 4; j++) {
                int d = dd[j];
                if (((d >> 4) & 7) == part && (unsigned)d < (unsigned)N_NODES) {
                    int s = ss[j];
                    if ((unsigned)s >= (unsigned)N_NODES) s = 0;
                    int pos = atomicAdd(&cursor[d], 1);
                    if (pos < CAP) adj[d * CAP + pos] = (u16)s;
                }
            }
        } else {
            for (int j = 0; j < 4; j++) {
                int ee = e + j;
                if (ee < N_EDGES) {
                    int d = ei[N_EDGES + ee];
                    if (((d >> 4) & 7) == part && (unsigned)d < (unsigned)N_NODES) {
                        int s = ei[ee];
                        if ((unsigned)s >= (unsigned)N_NODES) s = 0;
                        int pos = atomicAdd(&cursor[d], 1);
                        if (pos < CAP) adj[d * CAP + pos] = (u16)s;
                    }
                }
            }
        }
    }
}

// ---------------- MFMA GEMM, packed bf16 A, FULL column width per block ----------------
// Cb[M][N/2] = bf16(A[M][128] @ W[128][N]); Ab packed bf16 [M][64 uints].
// One block owns 64 rows x ALL N cols. __syncthreads() separates the last A-read
// from the first C-write, so IN-PLACE (Cb == Ab, N == 128) is race-free: no other
// block reads these rows, and within the block all reads precede all writes.
template <int N>
__global__ __launch_bounds__(256) void mfma_gemm_kernel(const uint32* __restrict__ Ab,
                                                        const uint32* __restrict__ WTb,
                                                        uint32* __restrict__ Cb, int M) {
    constexpr int NT = N / 64;  // col-tiles per wave
    const int tid = threadIdx.x;
    const int wave = tid >> 6;
    const int lane = tid & 63;
    const int r16 = lane & 15;
    const int g = lane >> 4;
    const int row0 = blockIdx.x * 64;

    const uint4* A4 = reinterpret_cast<const uint4*>(Ab);
    const uint4* B4 = reinterpret_cast<const uint4*>(WTb);

    f32x4 acc[4][NT];
#pragma unroll
    for (int m = 0; m < 4; m++)
#pragma unroll
        for (int nt = 0; nt < NT; nt++) acc[m][nt] = (f32x4){0.f, 0.f, 0.f, 0.f};

    int rowm[4];
#pragma unroll
    for (int m = 0; m < 4; m++) {
        int r = row0 + m * 16 + r16;
        rowm[m] = r < M ? r : M - 1;
    }
    union U { uint4 u; bf16x8 v; };
#pragma unroll
    for (int kt = 0; kt < 4; kt++) {
        U b[NT];
#pragma unroll
        for (int nt = 0; nt < NT; nt++)
            b[nt].u = B4[(size_t)(nt * 64 + wave * 16 + r16) * 16 + kt * 4 + g];
        U a[4];
#pragma unroll
        for (int m = 0; m < 4; m++) a[m].u = A4[(size_t)rowm[m] * 16 + kt * 4 + g];
#pragma unroll
        for (int m = 0; m < 4; m++)
#pragma unroll
            for (int nt = 0; nt < NT; nt++)
                acc[m][nt] = __builtin_amdgcn_mfma_f32_16x16x32_bf16(a[m].v, b[nt].v, acc[m][nt], 0, 0, 0);
    }
    __syncthreads();  // all A-reads done before any C-write (in-place safety)
#pragma unroll
    for (int m = 0; m < 4; m++)
#pragma unroll
        for (int nt = 0; nt < NT; nt++)
#pragma unroll
            for (int r = 0; r < 4; r++) {
                int row = row0 + m * 16 + g * 4 + r;
                if (row < M)
                    pack_store(Cb, N / 2, row, nt * 64 + wave * 16 + r16, r16, acc[m][nt][r]);
            }
}

// ---------------- slice-partitioned aggregate ----------------
// Feature dim split into 4 slices; blockIdx&7 -> XCD (round-robin heuristic),
// slice = (blockIdx&7)>>1 so each XCD's gather working set = F/4 feats of hwb
// (3.2 MB for F=128) -> fits 4 MB per-XCD L2 -> gathers become L2 hits.
// Lane layout: f = lane%L (uint2 within slice), j = lane/L (edge slot).
template <int F, bool WRITE_BF>
__global__ __launch_bounds__(256) void agg_slice_kernel(const uint32* __restrict__ hwb,
                                                        const u16* __restrict__ adj,
                                                        const int* __restrict__ deg,
                                                        const float* __restrict__ bias,
                                                        float* __restrict__ o_out,
                                                        uint32* __restrict__ obf) {
    constexpr int ROWU = F / 2;   // uints per row: 64 (F=128) / 32 (F=64)
    constexpr int SU = ROWU / 4;  // uints per slice: 16 / 8
    constexpr int L = SU / 2;     // lanes per edge: 8 / 4
    constexpr int E = 64 / L;     // edges per iter: 8 / 16

    const int x = blockIdx.x & 7;
    const int g = blockIdx.x >> 3;
    const int slice = x >> 1;
    const int h = x & 1;
    const int wave = threadIdx.x >> 6;
    const int lane = threadIdx.x & 63;
    const int f = lane % L;
    const int j = lane / L;

    const int nbase = g * 32 + h * 16 + wave * 4;
    const uint32* sbase = hwb + slice * SU + f * 2;

#pragma unroll
    for (int i = 0; i < 4; i++) {
        int n = nbase + i;
        if (n >= N_NODES) return;
        int d = __builtin_amdgcn_readfirstlane(deg[n]);
        if (d > CAP) d = CAP;
        int myslot = adj[n * CAP + lane];

        float a0 = 0.f, a1 = 0.f, a2 = 0.f, a3 = 0.f;
        int e = 0;
        for (; e + 2 * E <= d; e += 2 * E) {  // 2-deep pipelined batches
            int s0 = __shfl(myslot, e + j);
            int s1 = __shfl(myslot, e + E + j);
            uint2 v0 = *reinterpret_cast<const uint2*>(sbase + (size_t)s0 * ROWU);
            uint2 v1 = *reinterpret_cast<const uint2*>(sbase + (size_t)s1 * ROWU);
            a0 += bf16lo_to_f32(v0.x) + bf16lo_to_f32(v1.x);
            a1 += bf16hi_to_f32(v0.x) + bf16hi_to_f32(v1.x);
            a2 += bf16lo_to_f32(v0.y) + bf16lo_to_f32(v1.y);
            a3 += bf16hi_to_f32(v0.y) + bf16hi_to_f32(v1.y);
        }
        for (; e < d; e += E) {
            int idx = e + j;
            int s = __shfl(myslot, idx < d ? idx : e);
            uint2 v = make_uint2(0u, 0u);
            if (idx < d) v = *reinterpret_cast<const uint2*>(sbase + (size_t)s * ROWU);
            a0 += bf16lo_to_f32(v.x);
            a1 += bf16hi_to_f32(v.x);
            a2 += bf16lo_to_f32(v.y);
            a3 += bf16hi_to_f32(v.y);
        }
        // reduce across edge-slot groups (lanes differing above bit log2(L))
#pragma unroll
        for (int off = L; off < 64; off <<= 1) {
            a0 += __shfl_xor(a0, off);
            a1 += __shfl_xor(a1, off);
            a2 += __shfl_xor(a2, off);
            a3 += __shfl_xor(a3, off);
        }
        if (lane < L) {
            float4 b = *reinterpret_cast<const float4*>(&bias[slice * SU * 2 + f * 4]);
            a0 += b.x; a1 += b.y; a2 += b.z; a3 += b.w;
            *reinterpret_cast<float4*>(&o_out[(size_t)n * F + slice * SU * 2 + f * 4]) =
                make_float4(a0, a1, a2, a3);
            if (WRITE_BF) {
                uint2 p;
                p.x = f32_to_bf16_rne(a0) | (f32_to_bf16_rne(a1) << 16);
                p.y = f32_to_bf16_rne(a2) | (f32_to_bf16_rne(a3) << 16);
                *reinterpret_cast<uint2*>(&obf[(size_t)n * ROWU + slice * SU + f * 2]) = p;
            }
        }
    }
}

extern "C" void kernel_launch(void* const* d_in, const int* in_sizes, int n_in,
                              void* d_out, int out_size, void* d_ws, size_t ws_size,
                              hipStream_t stream) {
    const float* x  = (const float*)d_in[0];
    const int*   ei = (const int*)d_in[1];
    const float* W1 = (const float*)d_in[2];
    const float* b1 = (const float*)d_in[3];
    const float* W2 = (const float*)d_in[4];
    const float* b2 = (const float*)d_in[5];
    const float* W3 = (const float*)d_in[6];
    const float* b3 = (const float*)d_in[7];

    float* o1 = (float*)d_out;
    float* o2 = o1 + (size_t)N_NODES * 128;
    float* o3 = o2 + (size_t)N_NODES * 128;

    char* ws = (char*)d_ws;
    uint32* bufA   = (uint32*)(ws);                 // 12.8 MB
    uint32* bufB   = (uint32*)(ws + 12800000);      // 12.8 MB
    uint32* bufC   = (uint32*)(ws + 25600000);      // 6.4 MB
    u16*    adj    = (u16*)(ws + 32000000);         // 6.4 MB
    int*    cursor = (int*)(ws + 38400000);         // 200 KB
    uint32* wt1    = (uint32*)(ws + 38600000);      // 32 KB
    uint32* wt2    = (uint32*)(ws + 38632768);      // 32 KB
    uint32* wt3    = (uint32*)(ws + 38665536);      // 16 KB

    const int agg_grid = 1563 * 8;  // ceil(50000/32) node-groups x 8 slice/half blocks

    // 1. prep: zero cursor + WT tables
    prep_kernel<<<276, 256, 0, stream>>>(W1, W2, W3, wt1, wt2, wt3, cursor);
    // 2. fused adjacency build + gemm1 (x@W1 -> bufA)
    build_gemm1_kernel<<<GEMM1_BLOCKS + BUILD_CHUNKS * 8, 256, 0, stream>>>(x, wt1, bufA, ei, cursor, adj);
    // 3. agg1: gather bufA -> o1 (f32) + bufB (bf16 of o1)
    agg_slice_kernel<128, true><<<agg_grid, 256, 0, stream>>>(bufA, adj, cursor, b1, o1, bufB);
    // 4. gemm2: bufB @ W2 -> bufB (in-place safe: full-width blocks + syncthreads)
    mfma_gemm_kernel<128><<<GEMM1_BLOCKS, 256, 0, stream>>>(bufB, wt2, bufB, N_NODES);
    // 5. agg2: gather bufB -> o2 (f32) + bufA (bf16 of o2)
    agg_slice_kernel<128, true><<<agg_grid, 256, 0, stream>>>(bufB, adj, cursor, b2, o2, bufA);
    // 6. gemm3: bufA @ W3 -> bufC (N=64, out-of-place)
    mfma_gemm_kernel<64><<<GEMM1_BLOCKS, 256, 0, stream>>>(bufA, wt3, bufC, N_NODES);
    // 7. agg3: gather bufC -> o3
    agg_slice_kernel<64, false><<<agg_grid, 256, 0, stream>>>(bufC, adj, cursor, b3, o3, nullptr);
}

// Round 9
// 163.014 us; speedup vs baseline: 1.5172x; 1.5172x over previous
//
#include <hip/hip_runtime.h>

#define N_NODES 50000
#define N_EDGES 800000
#define CAP 64

typedef unsigned int uint32;
typedef unsigned short u16;

typedef __attribute__((ext_vector_type(8))) short bf16x8;
typedef __attribute__((ext_vector_type(4))) float f32x4;

__device__ __forceinline__ uint32 f32_to_bf16_rne(float f) {
    uint32 u = __float_as_uint(f);
    u += 0x7fffu + ((u >> 16) & 1u);
    return u >> 16;
}
__device__ __forceinline__ float bf16lo_to_f32(uint32 v) { return __uint_as_float(v << 16); }
__device__ __forceinline__ float bf16hi_to_f32(uint32 v) { return __uint_as_float(v & 0xffff0000u); }

// ---------------- prep: zero cursor + W -> WT bf16 tables (one launch) ----------------
__global__ __launch_bounds__(256) void prep_kernel(const float* __restrict__ W1,
                                                   const float* __restrict__ W2,
                                                   const float* __restrict__ W3,
                                                   uint32* __restrict__ wt1,
                                                   uint32* __restrict__ wt2,
                                                   uint32* __restrict__ wt3,
                                                   int* __restrict__ cursor) {
    int b = blockIdx.x, tid = threadIdx.x;
    if (b < 196) {
        int i = b * 256 + tid;
        if (i < N_NODES) cursor[i] = 0;
        return;
    }
    b -= 196;
    const float* W;
    uint32* WT;
    int N;
    if (b < 32) { W = W1; WT = wt1; N = 128; }
    else if (b < 64) { W = W2; WT = wt2; N = 128; b -= 32; }
    else { W = W3; WT = wt3; N = 64; b -= 64; }
    int i = b * 256 + tid;
    if (i >= N * 64) return;
    int n = i >> 6, p = i & 63;
    WT[n * 64 + p] = f32_to_bf16_rne(W[(2 * p) * N + n]) |
                     (f32_to_bf16_rne(W[(2 * p + 1) * N + n]) << 16);
}

// ---------------- MFMA epilogue helper: pack bf16 col-pairs, store ----------------
__device__ __forceinline__ void pack_store(uint32* __restrict__ Cb, int rowstride_u,
                                           int row, int col, int r16, float v) {
    float nb = __shfl_xor(v, 1);
    if ((r16 & 1) == 0) {
        uint32 p = f32_to_bf16_rne(v) | (f32_to_bf16_rne(nb) << 16);
        Cb[(size_t)row * rowstride_u + (col >> 1)] = p;
    }
}

// ---------------- gemm1 body: A f32 global, converted in-register (64-row blocks) ----
__device__ __forceinline__ void gemm1_body(const float* __restrict__ A,
                                           const uint32* __restrict__ WTb,
                                           uint32* __restrict__ Cb, int M, int bid) {
    constexpr int NT = 2;
    const int tid = threadIdx.x;
    const int wave = tid >> 6;
    const int lane = tid & 63;
    const int r16 = lane & 15;
    const int g = lane >> 4;
    const int row0 = bid * 64;

    const float4* A4 = reinterpret_cast<const float4*>(A);
    const uint4* B4 = reinterpret_cast<const uint4*>(WTb);

    f32x4 acc[4][NT];
#pragma unroll
    for (int m = 0; m < 4; m++)
#pragma unroll
        for (int nt = 0; nt < NT; nt++) acc[m][nt] = (f32x4){0.f, 0.f, 0.f, 0.f};

    int rowm[4];
#pragma unroll
    for (int m = 0; m < 4; m++) {
        int r = row0 + m * 16 + r16;
        rowm[m] = r < M ? r : M - 1;
    }
    union U { uint4 u; bf16x8 v; };
#pragma unroll
    for (int kt = 0; kt < 4; kt++) {
        U b[NT];
#pragma unroll
        for (int nt = 0; nt < NT; nt++)
            b[nt].u = B4[(size_t)(nt * 64 + wave * 16 + r16) * 16 + kt * 4 + g];
        U a[4];
#pragma unroll
        for (int m = 0; m < 4; m++) {
            float4 f0 = A4[(size_t)rowm[m] * 32 + kt * 8 + g * 2];
            float4 f1 = A4[(size_t)rowm[m] * 32 + kt * 8 + g * 2 + 1];
            a[m].u.x = f32_to_bf16_rne(f0.x) | (f32_to_bf16_rne(f0.y) << 16);
            a[m].u.y = f32_to_bf16_rne(f0.z) | (f32_to_bf16_rne(f0.w) << 16);
            a[m].u.z = f32_to_bf16_rne(f1.x) | (f32_to_bf16_rne(f1.y) << 16);
            a[m].u.w = f32_to_bf16_rne(f1.z) | (f32_to_bf16_rne(f1.w) << 16);
        }
#pragma unroll
        for (int m = 0; m < 4; m++)
#pragma unroll
            for (int nt = 0; nt < NT; nt++)
                acc[m][nt] = __builtin_amdgcn_mfma_f32_16x16x32_bf16(a[m].v, b[nt].v, acc[m][nt], 0, 0, 0);
    }
#pragma unroll
    for (int m = 0; m < 4; m++)
#pragma unroll
        for (int nt = 0; nt < NT; nt++)
#pragma unroll
            for (int r = 0; r < 4; r++) {
                int row = row0 + m * 16 + g * 4 + r;
                if (row < M)
                    pack_store(Cb, 64, row, nt * 64 + wave * 16 + r16, r16, acc[m][nt][r]);
            }
}

// ---------------- fused build (line-partitioned) + gemm1 ----------------
#define EPT 8
#define EPB (256 * EPT)
#define GEMM1_BLOCKS 782   // ceil(50000/64)
#define BUILD_CHUNKS 391   // ceil(800000/2048)

__global__ __launch_bounds__(256) void build_gemm1_kernel(const float* __restrict__ x,
                                                          const uint32* __restrict__ wt1,
                                                          uint32* __restrict__ hwb,
                                                          const int* __restrict__ ei,
                                                          int* __restrict__ cursor,
                                                          u16* __restrict__ adj) {
    if (blockIdx.x < GEMM1_BLOCKS) {
        gemm1_body(x, wt1, hwb, N_NODES, blockIdx.x);
        return;
    }
    const int bb = blockIdx.x - GEMM1_BLOCKS;
    const int part = bb & 7;
    const int chunk = bb >> 3;
    const int base = chunk * EPB + threadIdx.x * EPT;
#pragma unroll
    for (int i = 0; i < EPT; i += 4) {
        int e = base + i;
        if (e + 3 < N_EDGES) {
            int4 s4 = *reinterpret_cast<const int4*>(&ei[e]);
            int4 d4 = *reinterpret_cast<const int4*>(&ei[N_EDGES + e]);
            int ss[4] = {s4.x, s4.y, s4.z, s4.w};
            int dd[4] = {d4.x, d4.y, d4.z, d4.w};
#pragma unroll
            for (int j = 0; j < 4; j++) {
                int d = dd[j];
                if (((d >> 4) & 7) == part && (unsigned)d < (unsigned)N_NODES) {
                    int s = ss[j];
                    if ((unsigned)s >= (unsigned)N_NODES) s = 0;
                    int pos = atomicAdd(&cursor[d], 1);
                    if (pos < CAP) adj[d * CAP + pos] = (u16)s;
                }
            }
        } else {
            for (int j = 0; j < 4; j++) {
                int ee = e + j;
                if (ee < N_EDGES) {
                    int d = ei[N_EDGES + ee];
                    if (((d >> 4) & 7) == part && (unsigned)d < (unsigned)N_NODES) {
                        int s = ei[ee];
                        if ((unsigned)s >= (unsigned)N_NODES) s = 0;
                        int pos = atomicAdd(&cursor[d], 1);
                        if (pos < CAP) adj[d * CAP + pos] = (u16)s;
                    }
                }
            }
        }
    }
}

// ---- uint4 gather over 64-uint (128-feat) rows: 16 lanes/row, 4 edges/load ----
// f = lane&15 (uints 4f..4f+3), j = lane>>4 (edge slot). 4-deep: 16 edges in flight.
__device__ __forceinline__ void gather_q128(const uint32* __restrict__ sbase,
                                            int myslot, int d, int j, float a[8]) {
    int e = 0;
    for (; e + 16 <= d; e += 16) {
        int s0 = __shfl(myslot, e + j);
        int s1 = __shfl(myslot, e + 4 + j);
        int s2 = __shfl(myslot, e + 8 + j);
        int s3 = __shfl(myslot, e + 12 + j);
        uint4 v0 = *reinterpret_cast<const uint4*>(sbase + (size_t)s0 * 64);
        uint4 v1 = *reinterpret_cast<const uint4*>(sbase + (size_t)s1 * 64);
        uint4 v2 = *reinterpret_cast<const uint4*>(sbase + (size_t)s2 * 64);
        uint4 v3 = *reinterpret_cast<const uint4*>(sbase + (size_t)s3 * 64);
        a[0] += (bf16lo_to_f32(v0.x) + bf16lo_to_f32(v1.x)) + (bf16lo_to_f32(v2.x) + bf16lo_to_f32(v3.x));
        a[1] += (bf16hi_to_f32(v0.x) + bf16hi_to_f32(v1.x)) + (bf16hi_to_f32(v2.x) + bf16hi_to_f32(v3.x));
        a[2] += (bf16lo_to_f32(v0.y) + bf16lo_to_f32(v1.y)) + (bf16lo_to_f32(v2.y) + bf16lo_to_f32(v3.y));
        a[3] += (bf16hi_to_f32(v0.y) + bf16hi_to_f32(v1.y)) + (bf16hi_to_f32(v2.y) + bf16hi_to_f32(v3.y));
        a[4] += (bf16lo_to_f32(v0.z) + bf16lo_to_f32(v1.z)) + (bf16lo_to_f32(v2.z) + bf16lo_to_f32(v3.z));
        a[5] += (bf16hi_to_f32(v0.z) + bf16hi_to_f32(v1.z)) + (bf16hi_to_f32(v2.z) + bf16hi_to_f32(v3.z));
        a[6] += (bf16lo_to_f32(v0.w) + bf16lo_to_f32(v1.w)) + (bf16lo_to_f32(v2.w) + bf16lo_to_f32(v3.w));
        a[7] += (bf16hi_to_f32(v0.w) + bf16hi_to_f32(v1.w)) + (bf16hi_to_f32(v2.w) + bf16hi_to_f32(v3.w));
    }
    for (; e < d; e += 4) {
        int idx = e + j;
        int s = __shfl(myslot, idx < d ? idx : e);
        uint4 v = make_uint4(0u, 0u, 0u, 0u);
        if (idx < d) v = *reinterpret_cast<const uint4*>(sbase + (size_t)s * 64);
        a[0] += bf16lo_to_f32(v.x); a[1] += bf16hi_to_f32(v.x);
        a[2] += bf16lo_to_f32(v.y); a[3] += bf16hi_to_f32(v.y);
        a[4] += bf16lo_to_f32(v.z); a[5] += bf16hi_to_f32(v.z);
        a[6] += bf16lo_to_f32(v.w); a[7] += bf16hi_to_f32(v.w);
    }
}

// ---------------- fused aggregate(layer l) + gemm(layer l+1 messages) ----------------
// Block: 16 nodes (grid 3125 exact). 4 waves x 4 nodes, uint4 gather;
// then 16xN MFMA from LDS -> hw_out.
template <int N>
__global__ __launch_bounds__(256) void agg_gemm_kernel(const uint32* __restrict__ hw_in,
                                                       const u16* __restrict__ adj,
                                                       const int* __restrict__ deg,
                                                       const float* __restrict__ bias,
                                                       float* __restrict__ o_out,
                                                       const uint32* __restrict__ WTb,
                                                       uint32* __restrict__ hw_out) {
    constexpr int TPW = N / 64;  // 16-col tiles per wave: 2 (N=128) or 1 (N=64)
    constexpr int LDR = 68;
    __shared__ uint32 Asm[16 * LDR];

    const int tid = threadIdx.x;
    const int wave = tid >> 6;
    const int lane = tid & 63;
    const int f = lane & 15;
    const int j = lane >> 4;
    const int base = blockIdx.x * 16;
    const uint32* sbase = hw_in + f * 4;

#pragma unroll
    for (int i = 0; i < 4; i++) {
        int n = base + wave * 4 + i;
        int d = __builtin_amdgcn_readfirstlane(deg[n]);
        if (d > CAP) d = CAP;
        int myslot = adj[n * CAP + lane];
        float a[8] = {0.f, 0.f, 0.f, 0.f, 0.f, 0.f, 0.f, 0.f};
        gather_q128(sbase, myslot, d, j, a);
#pragma unroll
        for (int off = 16; off < 64; off <<= 1)
#pragma unroll
            for (int k = 0; k < 8; k++) a[k] += __shfl_xor(a[k], off);
        if (lane < 16) {
            float4 b0 = *reinterpret_cast<const float4*>(&bias[f * 8]);
            float4 b1 = *reinterpret_cast<const float4*>(&bias[f * 8 + 4]);
            a[0] += b0.x; a[1] += b0.y; a[2] += b0.z; a[3] += b0.w;
            a[4] += b1.x; a[5] += b1.y; a[6] += b1.z; a[7] += b1.w;
            *reinterpret_cast<float4*>(&o_out[(size_t)n * 128 + f * 8]) =
                make_float4(a[0], a[1], a[2], a[3]);
            *reinterpret_cast<float4*>(&o_out[(size_t)n * 128 + f * 8 + 4]) =
                make_float4(a[4], a[5], a[6], a[7]);
            uint4 p;
            p.x = f32_to_bf16_rne(a[0]) | (f32_to_bf16_rne(a[1]) << 16);
            p.y = f32_to_bf16_rne(a[2]) | (f32_to_bf16_rne(a[3]) << 16);
            p.z = f32_to_bf16_rne(a[4]) | (f32_to_bf16_rne(a[5]) << 16);
            p.w = f32_to_bf16_rne(a[6]) | (f32_to_bf16_rne(a[7]) << 16);
            *reinterpret_cast<uint4*>(&Asm[(wave * 4 + i) * LDR + f * 4]) = p;
        }
    }
    __syncthreads();

    // ---- GEMM 16 x N from LDS ----
    const int r16 = lane & 15;
    const int g = lane >> 4;
    const uint4* B4 = reinterpret_cast<const uint4*>(WTb);

    f32x4 acc[TPW];
#pragma unroll
    for (int nt = 0; nt < TPW; nt++) acc[nt] = (f32x4){0.f, 0.f, 0.f, 0.f};

    union U { uint4 u; bf16x8 v; };
#pragma unroll
    for (int kt = 0; kt < 4; kt++) {
        U a;
        a.u = *reinterpret_cast<const uint4*>(&Asm[r16 * LDR + (kt * 4 + g) * 4]);
        U b[TPW];
#pragma unroll
        for (int nt = 0; nt < TPW; nt++) {
            int col = (wave * TPW + nt) * 16 + r16;
            b[nt].u = B4[(size_t)col * 16 + kt * 4 + g];
        }
#pragma unroll
        for (int nt = 0; nt < TPW; nt++)
            acc[nt] = __builtin_amdgcn_mfma_f32_16x16x32_bf16(a.v, b[nt].v, acc[nt], 0, 0, 0);
    }
#pragma unroll
    for (int nt = 0; nt < TPW; nt++)
#pragma unroll
        for (int r = 0; r < 4; r++) {
            int row = base + g * 4 + r;
            pack_store(hw_out, N / 2, row, (wave * TPW + nt) * 16 + r16, r16, acc[nt][r]);
        }
}

// ---------------- final aggregate F=64: 1 node/wave, uint4 gather (8 lanes/row) ----
__global__ __launch_bounds__(256) void aggregate64_kernel(const uint32* __restrict__ hwb,
                                                          const u16* __restrict__ adj,
                                                          const int* __restrict__ deg,
                                                          const float* __restrict__ bias,
                                                          float* __restrict__ out) {
    int n = (blockIdx.x * blockDim.x + threadIdx.x) >> 6;
    if (n >= N_NODES) return;
    const int lane = threadIdx.x & 63;
    const int f = lane & 7;
    const int j = lane >> 3;  // 0..7 edge slots
    int d = __builtin_amdgcn_readfirstlane(deg[n]);
    if (d > CAP) d = CAP;
    int myslot = adj[n * CAP + lane];
    const uint32* sbase = hwb + f * 4;

    float a[8] = {0.f, 0.f, 0.f, 0.f, 0.f, 0.f, 0.f, 0.f};
    int e = 0;
    for (; e + 16 <= d; e += 16) {
        int s0 = __shfl(myslot, e + j);
        int s1 = __shfl(myslot, e + 8 + j);
        uint4 v0 = *reinterpret_cast<const uint4*>(sbase + (size_t)s0 * 32);
        uint4 v1 = *reinterpret_cast<const uint4*>(sbase + (size_t)s1 * 32);
        a[0] += bf16lo_to_f32(v0.x) + bf16lo_to_f32(v1.x);
        a[1] += bf16hi_to_f32(v0.x) + bf16hi_to_f32(v1.x);
        a[2] += bf16lo_to_f32(v0.y) + bf16lo_to_f32(v1.y);
        a[3] += bf16hi_to_f32(v0.y) + bf16hi_to_f32(v1.y);
        a[4] += bf16lo_to_f32(v0.z) + bf16lo_to_f32(v1.z);
        a[5] += bf16hi_to_f32(v0.z) + bf16hi_to_f32(v1.z);
        a[6] += bf16lo_to_f32(v0.w) + bf16lo_to_f32(v1.w);
        a[7] += bf16hi_to_f32(v0.w) + bf16hi_to_f32(v1.w);
    }
    for (; e < d; e += 8) {
        int idx = e + j;
        int s = __shfl(myslot, idx < d ? idx : e);
        uint4 v = make_uint4(0u, 0u, 0u, 0u);
        if (idx < d) v = *reinterpret_cast<const uint4*>(sbase + (size_t)s * 32);
        a[0] += bf16lo_to_f32(v.x); a[1] += bf16hi_to_f32(v.x);
        a[2] += bf16lo_to_f32(v.y); a[3] += bf16hi_to_f32(v.y);
        a[4] += bf16lo_to_f32(v.z); a[5] += bf16hi_to_f32(v.z);
        a[6] += bf16lo_to_f32(v.w); a[7] += bf16hi_to_f32(v.w);
    }
#pragma unroll
    for (int off = 8; off < 64; off <<= 1)
#pragma unroll
        for (int k = 0; k < 8; k++) a[k] += __shfl_xor(a[k], off);
    if (lane < 8) {
        float4 b0 = *reinterpret_cast<const float4*>(&bias[f * 8]);
        float4 b1 = *reinterpret_cast<const float4*>(&bias[f * 8 + 4]);
        *reinterpret_cast<float4*>(&out[(size_t)n * 64 + f * 8]) =
            make_float4(a[0] + b0.x, a[1] + b0.y, a[2] + b0.z, a[3] + b0.w);
        *reinterpret_cast<float4*>(&out[(size_t)n * 64 + f * 8 + 4]) =
            make_float4(a[4] + b1.x, a[5] + b1.y, a[6] + b1.z, a[7] + b1.w);
    }
}

extern "C" void kernel_launch(void* const* d_in, const int* in_sizes, int n_in,
                              void* d_out, int out_size, void* d_ws, size_t ws_size,
                              hipStream_t stream) {
    const float* x  = (const float*)d_in[0];
    const int*   ei = (const int*)d_in[1];
    const float* W1 = (const float*)d_in[2];
    const float* b1 = (const float*)d_in[3];
    const float* W2 = (const float*)d_in[4];
    const float* b2 = (const float*)d_in[5];
    const float* W3 = (const float*)d_in[6];
    const float* b3 = (const float*)d_in[7];

    float* o1 = (float*)d_out;
    float* o2 = o1 + (size_t)N_NODES * 128;
    float* o3 = o2 + (size_t)N_NODES * 128;

    char* ws = (char*)d_ws;
    uint32* hwbA   = (uint32*)(ws);                 // 12.8 MB
    uint32* hwbB   = (uint32*)(ws + 12800000);      // 12.8 MB
    u16*    adj    = (u16*)(ws + 25600000);         // 6.4 MB
    int*    cursor = (int*)(ws + 32000000);         // 200 KB
    uint32* wt1    = (uint32*)(ws + 32200000);      // 32 KB
    uint32* wt2    = (uint32*)(ws + 32232768);      // 32 KB
    uint32* wt3    = (uint32*)(ws + 32265536);      // 16 KB

    // 1. prep: zero cursor + WT tables
    prep_kernel<<<276, 256, 0, stream>>>(W1, W2, W3, wt1, wt2, wt3, cursor);
    // 2. fused adjacency build + gemm1 (x@W1 -> hwbA)
    build_gemm1_kernel<<<GEMM1_BLOCKS + BUILD_CHUNKS * 8, 256, 0, stream>>>(x, wt1, hwbA, ei, cursor, adj);
    // 3. agg1 (+b1 -> o1) fused with gemm2 -> hwbB   (3125 blocks, 16 nodes each)
    agg_gemm_kernel<128><<<3125, 256, 0, stream>>>(hwbA, adj, cursor, b1, o1, wt2, hwbB);
    // 4. agg2 (+b2 -> o2) fused with gemm3 -> hwbA
    agg_gemm_kernel<64><<<3125, 256, 0, stream>>>(hwbB, adj, cursor, b2, o2, wt3, hwbA);
    // 5. agg3 (+b3 -> o3)
    aggregate64_kernel<<<12500, 256, 0, stream>>>(hwbA, adj, cursor, b3, o3);
}

// Round 10
// 145.969 us; speedup vs baseline: 1.6944x; 1.1168x over previous
//
#include <hip/hip_runtime.h>

#define N_NODES 50000
#define N_EDGES 800000
#define CAP 64
#define NBUCK 391      // ceil(50000/128) buckets of 128 nodes
#define BCAP 3072      // slots/bucket; Poisson(2048), 22 sigma of headroom

typedef unsigned int uint32;
typedef unsigned short u16;

typedef __attribute__((ext_vector_type(8))) short bf16x8;
typedef __attribute__((ext_vector_type(4))) float f32x4;

__device__ __forceinline__ uint32 f32_to_bf16_rne(float f) {
    uint32 u = __float_as_uint(f);
    u += 0x7fffu + ((u >> 16) & 1u);
    return u >> 16;
}
__device__ __forceinline__ float bf16lo_to_f32(uint32 v) { return __uint_as_float(v << 16); }
__device__ __forceinline__ float bf16hi_to_f32(uint32 v) { return __uint_as_float(v & 0xffff0000u); }

// ---------------- prep: zero bucket cursors + W -> WT bf16 tables ----------------
__global__ __launch_bounds__(256) void prep_kernel(const float* __restrict__ W1,
                                                   const float* __restrict__ W2,
                                                   const float* __restrict__ W3,
                                                   uint32* __restrict__ wt1,
                                                   uint32* __restrict__ wt2,
                                                   uint32* __restrict__ wt3,
                                                   uint32* __restrict__ bcursor) {
    int b = blockIdx.x, tid = threadIdx.x;
    if (b < 2) {
        int i = b * 256 + tid;
        if (i < NBUCK) bcursor[i] = 0;
        return;
    }
    b -= 2;
    const float* W;
    uint32* WT;
    int N;
    if (b < 32) { W = W1; WT = wt1; N = 128; }
    else if (b < 64) { W = W2; WT = wt2; N = 128; b -= 32; }
    else { W = W3; WT = wt3; N = 64; b -= 64; }
    int i = b * 256 + tid;
    if (i >= N * 64) return;
    int n = i >> 6, p = i & 63;
    WT[n * 64 + p] = f32_to_bf16_rne(W[(2 * p) * N + n]) |
                     (f32_to_bf16_rne(W[(2 * p + 1) * N + n]) << 16);
}

// ---------------- MFMA epilogue helper: pack bf16 col-pairs, store ----------------
__device__ __forceinline__ void pack_store(uint32* __restrict__ Cb, int rowstride_u,
                                           int row, int col, int r16, float v) {
    float nb = __shfl_xor(v, 1);
    if ((r16 & 1) == 0) {
        uint32 p = f32_to_bf16_rne(v) | (f32_to_bf16_rne(nb) << 16);
        Cb[(size_t)row * rowstride_u + (col >> 1)] = p;
    }
}

// ---------------- gemm1 body: A f32 global, converted in-register (64-row blocks) ----
__device__ __forceinline__ void gemm1_body(const float* __restrict__ A,
                                           const uint32* __restrict__ WTb,
                                           uint32* __restrict__ Cb, int M, int bid) {
    constexpr int NT = 2;
    const int tid = threadIdx.x;
    const int wave = tid >> 6;
    const int lane = tid & 63;
    const int r16 = lane & 15;
    const int g = lane >> 4;
    const int row0 = bid * 64;

    const float4* A4 = reinterpret_cast<const float4*>(A);
    const uint4* B4 = reinterpret_cast<const uint4*>(WTb);

    f32x4 acc[4][NT];
#pragma unroll
    for (int m = 0; m < 4; m++)
#pragma unroll
        for (int nt = 0; nt < NT; nt++) acc[m][nt] = (f32x4){0.f, 0.f, 0.f, 0.f};

    int rowm[4];
#pragma unroll
    for (int m = 0; m < 4; m++) {
        int r = row0 + m * 16 + r16;
        rowm[m] = r < M ? r : M - 1;
    }
    union U { uint4 u; bf16x8 v; };
#pragma unroll
    for (int kt = 0; kt < 4; kt++) {
        U b[NT];
#pragma unroll
        for (int nt = 0; nt < NT; nt++)
            b[nt].u = B4[(size_t)(nt * 64 + wave * 16 + r16) * 16 + kt * 4 + g];
        U a[4];
#pragma unroll
        for (int m = 0; m < 4; m++) {
            float4 f0 = A4[(size_t)rowm[m] * 32 + kt * 8 + g * 2];
            float4 f1 = A4[(size_t)rowm[m] * 32 + kt * 8 + g * 2 + 1];
            a[m].u.x = f32_to_bf16_rne(f0.x) | (f32_to_bf16_rne(f0.y) << 16);
            a[m].u.y = f32_to_bf16_rne(f0.z) | (f32_to_bf16_rne(f0.w) << 16);
            a[m].u.z = f32_to_bf16_rne(f1.x) | (f32_to_bf16_rne(f1.y) << 16);
            a[m].u.w = f32_to_bf16_rne(f1.z) | (f32_to_bf16_rne(f1.w) << 16);
        }
#pragma unroll
        for (int m = 0; m < 4; m++)
#pragma unroll
            for (int nt = 0; nt < NT; nt++)
                acc[m][nt] = __builtin_amdgcn_mfma_f32_16x16x32_bf16(a[m].v, b[nt].v, acc[m][nt], 0, 0, 0);
    }
#pragma unroll
    for (int m = 0; m < 4; m++)
#pragma unroll
        for (int nt = 0; nt < NT; nt++)
#pragma unroll
            for (int r = 0; r < 4; r++) {
                int row = row0 + m * 16 + g * 4 + r;
                if (row < M)
                    pack_store(Cb, 64, row, nt * 64 + wave * 16 + r16, r16, acc[m][nt][r]);
            }
}

// ---------------- fused edge-bucket scatter + gemm1 ----------------
// Scatter blocks: LDS histogram over NBUCK buckets -> one global atomicAdd per
// touched bucket (coalesced) -> packed edge (src | dstLocal<<16) into bucket array.
// Edge list read ONCE; no per-node global atomics.
#define GEMM1_BLOCKS 782     // ceil(50000/64)
#define SCAT_BLOCKS 391      // ceil(800000/2048)

__global__ __launch_bounds__(256) void scatter_gemm1_kernel(const float* __restrict__ x,
                                                            const uint32* __restrict__ wt1,
                                                            uint32* __restrict__ hwb,
                                                            const int* __restrict__ ei,
                                                            uint32* __restrict__ bcursor,
                                                            uint32* __restrict__ bedges) {
    if (blockIdx.x < GEMM1_BLOCKS) {
        gemm1_body(x, wt1, hwb, N_NODES, blockIdx.x);
        return;
    }
    const int chunk = blockIdx.x - GEMM1_BLOCKS;
    __shared__ uint32 hist[NBUCK];
    const int tid = threadIdx.x;
    for (int t = tid; t < NBUCK; t += 256) hist[t] = 0;
    __syncthreads();

    uint32 meta[8], payload[8];
    const int base = chunk * 2048;
#pragma unroll
    for (int k = 0; k < 8; k++) {
        int e = base + k * 256 + tid;
        meta[k] = 0xFFFFFFFFu;
        if (e < N_EDGES) {
            int s = ei[e];
            int dt = ei[N_EDGES + e];
            if ((unsigned)dt < (unsigned)N_NODES) {
                if ((unsigned)s >= (unsigned)N_NODES) s = 0;
                int b = dt >> 7;
                uint32 slot = atomicAdd(&hist[b], 1u);   // LDS atomic
                meta[k] = (uint32)b | (slot << 9);
                payload[k] = (uint32)s | ((uint32)(dt & 127) << 16);
            }
        }
    }
    __syncthreads();
    for (int t = tid; t < NBUCK; t += 256) {
        uint32 h = hist[t];
        uint32 g = h ? atomicAdd(&bcursor[t], h) : 0u;   // global, coalesced batch
        hist[t] = g;                                     // now holds global base
    }
    __syncthreads();
#pragma unroll
    for (int k = 0; k < 8; k++) {
        if (meta[k] != 0xFFFFFFFFu) {
            uint32 b = meta[k] & 511u;
            uint32 addr = hist[b] + (meta[k] >> 9);
            if (addr < BCAP) bedges[(size_t)b * BCAP + addr] = payload[k];
        }
    }
}

// ---------------- bucket -> adjacency rows (LDS cursors, zero global atomics) ----
__global__ __launch_bounds__(256) void bucket_build_kernel(const uint32* __restrict__ bedges,
                                                           const uint32* __restrict__ bcursor,
                                                           u16* __restrict__ adj,
                                                           int* __restrict__ deg) {
    const int b = blockIdx.x;
    __shared__ uint32 cur[128];
    const int tid = threadIdx.x;
    if (tid < 128) cur[tid] = 0;
    __syncthreads();
    uint32 cnt = bcursor[b];
    if (cnt > BCAP) cnt = BCAP;
    const uint32* be = bedges + (size_t)b * BCAP;
    for (uint32 i = tid; i < cnt; i += 256) {
        uint32 p = be[i];
        uint32 dl = p >> 16;
        uint32 s = p & 0xFFFFu;
        uint32 pos = atomicAdd(&cur[dl], 1u);            // LDS atomic
        if (pos < CAP) adj[((size_t)(b * 128 + dl)) * CAP + pos] = (u16)s;
    }
    __syncthreads();
    if (tid < 128) {
        int n = b * 128 + tid;
        if (n < N_NODES) deg[n] = (int)cur[tid];
    }
}

// ---- uint4 gather over 64-uint (128-feat) rows: 16 lanes/row, 4 edges/load ----
__device__ __forceinline__ void gather_q128(const uint32* __restrict__ sbase,
                                            int myslot, int d, int j, float a[8]) {
    int e = 0;
    for (; e + 16 <= d; e += 16) {
        int s0 = __shfl(myslot, e + j);
        int s1 = __shfl(myslot, e + 4 + j);
        int s2 = __shfl(myslot, e + 8 + j);
        int s3 = __shfl(myslot, e + 12 + j);
        uint4 v0 = *reinterpret_cast<const uint4*>(sbase + (size_t)s0 * 64);
        uint4 v1 = *reinterpret_cast<const uint4*>(sbase + (size_t)s1 * 64);
        uint4 v2 = *reinterpret_cast<const uint4*>(sbase + (size_t)s2 * 64);
        uint4 v3 = *reinterpret_cast<const uint4*>(sbase + (size_t)s3 * 64);
        a[0] += (bf16lo_to_f32(v0.x) + bf16lo_to_f32(v1.x)) + (bf16lo_to_f32(v2.x) + bf16lo_to_f32(v3.x));
        a[1] += (bf16hi_to_f32(v0.x) + bf16hi_to_f32(v1.x)) + (bf16hi_to_f32(v2.x) + bf16hi_to_f32(v3.x));
        a[2] += (bf16lo_to_f32(v0.y) + bf16lo_to_f32(v1.y)) + (bf16lo_to_f32(v2.y) + bf16lo_to_f32(v3.y));
        a[3] += (bf16hi_to_f32(v0.y) + bf16hi_to_f32(v1.y)) + (bf16hi_to_f32(v2.y) + bf16hi_to_f32(v3.y));
        a[4] += (bf16lo_to_f32(v0.z) + bf16lo_to_f32(v1.z)) + (bf16lo_to_f32(v2.z) + bf16lo_to_f32(v3.z));
        a[5] += (bf16hi_to_f32(v0.z) + bf16hi_to_f32(v1.z)) + (bf16hi_to_f32(v2.z) + bf16hi_to_f32(v3.z));
        a[6] += (bf16lo_to_f32(v0.w) + bf16lo_to_f32(v1.w)) + (bf16lo_to_f32(v2.w) + bf16lo_to_f32(v3.w));
        a[7] += (bf16hi_to_f32(v0.w) + bf16hi_to_f32(v1.w)) + (bf16hi_to_f32(v2.w) + bf16hi_to_f32(v3.w));
    }
    for (; e < d; e += 4) {
        int idx = e + j;
        int s = __shfl(myslot, idx < d ? idx : e);
        uint4 v = make_uint4(0u, 0u, 0u, 0u);
        if (idx < d) v = *reinterpret_cast<const uint4*>(sbase + (size_t)s * 64);
        a[0] += bf16lo_to_f32(v.x); a[1] += bf16hi_to_f32(v.x);
        a[2] += bf16lo_to_f32(v.y); a[3] += bf16hi_to_f32(v.y);
        a[4] += bf16lo_to_f32(v.z); a[5] += bf16hi_to_f32(v.z);
        a[6] += bf16lo_to_f32(v.w); a[7] += bf16hi_to_f32(v.w);
    }
}

// ---------------- fused aggregate(layer l) + gemm(layer l+1 messages) ----------------
template <int N>
__global__ __launch_bounds__(256) void agg_gemm_kernel(const uint32* __restrict__ hw_in,
                                                       const u16* __restrict__ adj,
                                                       const int* __restrict__ deg,
                                                       const float* __restrict__ bias,
                                                       float* __restrict__ o_out,
                                                       const uint32* __restrict__ WTb,
                                                       uint32* __restrict__ hw_out) {
    constexpr int TPW = N / 64;
    constexpr int LDR = 68;
    __shared__ uint32 Asm[16 * LDR];

    const int tid = threadIdx.x;
    const int wave = tid >> 6;
    const int lane = tid & 63;
    const int f = lane & 15;
    const int j = lane >> 4;
    const int base = blockIdx.x * 16;
    const uint32* sbase = hw_in + f * 4;

#pragma unroll
    for (int i = 0; i < 4; i++) {
        int n = base + wave * 4 + i;
        int d = __builtin_amdgcn_readfirstlane(deg[n]);
        if (d > CAP) d = CAP;
        int myslot = adj[n * CAP + lane];
        float a[8] = {0.f, 0.f, 0.f, 0.f, 0.f, 0.f, 0.f, 0.f};
        gather_q128(sbase, myslot, d, j, a);
#pragma unroll
        for (int off = 16; off < 64; off <<= 1)
#pragma unroll
            for (int k = 0; k < 8; k++) a[k] += __shfl_xor(a[k], off);
        if (lane < 16) {
            float4 b0 = *reinterpret_cast<const float4*>(&bias[f * 8]);
            float4 b1 = *reinterpret_cast<const float4*>(&bias[f * 8 + 4]);
            a[0] += b0.x; a[1] += b0.y; a[2] += b0.z; a[3] += b0.w;
            a[4] += b1.x; a[5] += b1.y; a[6] += b1.z; a[7] += b1.w;
            *reinterpret_cast<float4*>(&o_out[(size_t)n * 128 + f * 8]) =
                make_float4(a[0], a[1], a[2], a[3]);
            *reinterpret_cast<float4*>(&o_out[(size_t)n * 128 + f * 8 + 4]) =
                make_float4(a[4], a[5], a[6], a[7]);
            uint4 p;
            p.x = f32_to_bf16_rne(a[0]) | (f32_to_bf16_rne(a[1]) << 16);
            p.y = f32_to_bf16_rne(a[2]) | (f32_to_bf16_rne(a[3]) << 16);
            p.z = f32_to_bf16_rne(a[4]) | (f32_to_bf16_rne(a[5]) << 16);
            p.w = f32_to_bf16_rne(a[6]) | (f32_to_bf16_rne(a[7]) << 16);
            *reinterpret_cast<uint4*>(&Asm[(wave * 4 + i) * LDR + f * 4]) = p;
        }
    }
    __syncthreads();

    const int r16 = lane & 15;
    const int g = lane >> 4;
    const uint4* B4 = reinterpret_cast<const uint4*>(WTb);

    f32x4 acc[TPW];
#pragma unroll
    for (int nt = 0; nt < TPW; nt++) acc[nt] = (f32x4){0.f, 0.f, 0.f, 0.f};

    union U { uint4 u; bf16x8 v; };
#pragma unroll
    for (int kt = 0; kt < 4; kt++) {
        U a;
        a.u = *reinterpret_cast<const uint4*>(&Asm[r16 * LDR + (kt * 4 + g) * 4]);
        U b[TPW];
#pragma unroll
        for (int nt = 0; nt < TPW; nt++) {
            int col = (wave * TPW + nt) * 16 + r16;
            b[nt].u = B4[(size_t)col * 16 + kt * 4 + g];
        }
#pragma unroll
        for (int nt = 0; nt < TPW; nt++)
            acc[nt] = __builtin_amdgcn_mfma_f32_16x16x32_bf16(a.v, b[nt].v, acc[nt], 0, 0, 0);
    }
#pragma unroll
    for (int nt = 0; nt < TPW; nt++)
#pragma unroll
        for (int r = 0; r < 4; r++) {
            int row = base + g * 4 + r;
            pack_store(hw_out, N / 2, row, (wave * TPW + nt) * 16 + r16, r16, acc[nt][r]);
        }
}

// ---------------- final aggregate F=64: 1 node/wave, uint4 gather (8 lanes/row) ----
__global__ __launch_bounds__(256) void aggregate64_kernel(const uint32* __restrict__ hwb,
                                                          const u16* __restrict__ adj,
                                                          const int* __restrict__ deg,
                                                          const float* __restrict__ bias,
                                                          float* __restrict__ out) {
    int n = (blockIdx.x * blockDim.x + threadIdx.x) >> 6;
    if (n >= N_NODES) return;
    const int lane = threadIdx.x & 63;
    const int f = lane & 7;
    const int j = lane >> 3;
    int d = __builtin_amdgcn_readfirstlane(deg[n]);
    if (d > CAP) d = CAP;
    int myslot = adj[n * CAP + lane];
    const uint32* sbase = hwb + f * 4;

    float a[8] = {0.f, 0.f, 0.f, 0.f, 0.f, 0.f, 0.f, 0.f};
    int e = 0;
    for (; e + 16 <= d; e += 16) {
        int s0 = __shfl(myslot, e + j);
        int s1 = __shfl(myslot, e + 8 + j);
        uint4 v0 = *reinterpret_cast<const uint4*>(sbase + (size_t)s0 * 32);
        uint4 v1 = *reinterpret_cast<const uint4*>(sbase + (size_t)s1 * 32);
        a[0] += bf16lo_to_f32(v0.x) + bf16lo_to_f32(v1.x);
        a[1] += bf16hi_to_f32(v0.x) + bf16hi_to_f32(v1.x);
        a[2] += bf16lo_to_f32(v0.y) + bf16lo_to_f32(v1.y);
        a[3] += bf16hi_to_f32(v0.y) + bf16hi_to_f32(v1.y);
        a[4] += bf16lo_to_f32(v0.z) + bf16lo_to_f32(v1.z);
        a[5] += bf16hi_to_f32(v0.z) + bf16hi_to_f32(v1.z);
        a[6] += bf16lo_to_f32(v0.w) + bf16lo_to_f32(v1.w);
        a[7] += bf16hi_to_f32(v0.w) + bf16hi_to_f32(v1.w);
    }
    for (; e < d; e += 8) {
        int idx = e + j;
        int s = __shfl(myslot, idx < d ? idx : e);
        uint4 v = make_uint4(0u, 0u, 0u, 0u);
        if (idx < d) v = *reinterpret_cast<const uint4*>(sbase + (size_t)s * 32);
        a[0] += bf16lo_to_f32(v.x); a[1] += bf16hi_to_f32(v.x);
        a[2] += bf16lo_to_f32(v.y); a[3] += bf16hi_to_f32(v.y);
        a[4] += bf16lo_to_f32(v.z); a[5] += bf16hi_to_f32(v.z);
        a[6] += bf16lo_to_f32(v.w); a[7] += bf16hi_to_f32(v.w);
    }
#pragma unroll
    for (int off = 8; off < 64; off <<= 1)
#pragma unroll
        for (int k = 0; k < 8; k++) a[k] += __shfl_xor(a[k], off);
    if (lane < 8) {
        float4 b0 = *reinterpret_cast<const float4*>(&bias[f * 8]);
        float4 b1 = *reinterpret_cast<const float4*>(&bias[f * 8 + 4]);
        *reinterpret_cast<float4*>(&out[(size_t)n * 64 + f * 8]) =
            make_float4(a[0] + b0.x, a[1] + b0.y, a[2] + b0.z, a[3] + b0.w);
        *reinterpret_cast<float4*>(&out[(size_t)n * 64 + f * 8 + 4]) =
            make_float4(a[4] + b1.x, a[5] + b1.y, a[6] + b1.z, a[7] + b1.w);
    }
}

extern "C" void kernel_launch(void* const* d_in, const int* in_sizes, int n_in,
                              void* d_out, int out_size, void* d_ws, size_t ws_size,
                              hipStream_t stream) {
    const float* x  = (const float*)d_in[0];
    const int*   ei = (const int*)d_in[1];
    const float* W1 = (const float*)d_in[2];
    const float* b1 = (const float*)d_in[3];
    const float* W2 = (const float*)d_in[4];
    const float* b2 = (const float*)d_in[5];
    const float* W3 = (const float*)d_in[6];
    const float* b3 = (const float*)d_in[7];

    float* o1 = (float*)d_out;
    float* o2 = o1 + (size_t)N_NODES * 128;
    float* o3 = o2 + (size_t)N_NODES * 128;

    char* ws = (char*)d_ws;
    uint32* hwbA    = (uint32*)(ws);                 // 12.8 MB
    uint32* hwbB    = (uint32*)(ws + 12800000);      // 12.8 MB
    u16*    adj     = (u16*)(ws + 25600000);         // 6.4 MB
    int*    deg     = (int*)(ws + 32000000);         // 200 KB
    uint32* bedges  = (uint32*)(ws + 32200000);      // 391*3072*4 = 4.8 MB
    uint32* bcursor = (uint32*)(ws + 37004608);      // 1.6 KB
    uint32* wt1     = (uint32*)(ws + 37006464);      // 32 KB
    uint32* wt2     = (uint32*)(ws + 37039232);      // 32 KB
    uint32* wt3     = (uint32*)(ws + 37072000);      // 16 KB

    // 1. prep: zero bucket cursors + WT tables
    prep_kernel<<<82, 256, 0, stream>>>(W1, W2, W3, wt1, wt2, wt3, bcursor);
    // 2. fused edge-bucket scatter + gemm1 (x@W1 -> hwbA)
    scatter_gemm1_kernel<<<GEMM1_BLOCKS + SCAT_BLOCKS, 256, 0, stream>>>(x, wt1, hwbA, ei, bcursor, bedges);
    // 3. bucket -> adjacency rows + deg (LDS cursors only)
    bucket_build_kernel<<<NBUCK, 256, 0, stream>>>(bedges, bcursor, adj, deg);
    // 4. agg1 (+b1 -> o1) fused with gemm2 -> hwbB
    agg_gemm_kernel<128><<<3125, 256, 0, stream>>>(hwbA, adj, deg, b1, o1, wt2, hwbB);
    // 5. agg2 (+b2 -> o2) fused with gemm3 -> hwbA
    agg_gemm_kernel<64><<<3125, 256, 0, stream>>>(hwbB, adj, deg, b2, o2, wt3, hwbA);
    // 6. agg3 (+b3 -> o3)
    aggregate64_kernel<<<12500, 256, 0, stream>>>(hwbA, adj, deg, b3, o3);
}

// Round 11
// 143.968 us; speedup vs baseline: 1.7180x; 1.0139x over previous
//
#include <hip/hip_runtime.h>

#define N_NODES 50000
#define N_EDGES 800000
#define CAP 64
#define NBUCK 391      // ceil(50000/128) buckets of 128 nodes
#define BCAP 3072      // slots/bucket; Poisson(2048), 22 sigma of headroom

typedef unsigned int uint32;
typedef unsigned short u16;

typedef __attribute__((ext_vector_type(8))) short bf16x8;
typedef __attribute__((ext_vector_type(4))) float f32x4;

__device__ __forceinline__ uint32 f32_to_bf16_rne(float f) {
    uint32 u = __float_as_uint(f);
    u += 0x7fffu + ((u >> 16) & 1u);
    return u >> 16;
}
__device__ __forceinline__ float bf16lo_to_f32(uint32 v) { return __uint_as_float(v << 16); }
__device__ __forceinline__ float bf16hi_to_f32(uint32 v) { return __uint_as_float(v & 0xffff0000u); }

// ---------------- prep: zero bucket cursors + W -> WT bf16 tables ----------------
__global__ __launch_bounds__(256) void prep_kernel(const float* __restrict__ W1,
                                                   const float* __restrict__ W2,
                                                   const float* __restrict__ W3,
                                                   uint32* __restrict__ wt1,
                                                   uint32* __restrict__ wt2,
                                                   uint32* __restrict__ wt3,
                                                   uint32* __restrict__ bcursor) {
    int b = blockIdx.x, tid = threadIdx.x;
    if (b < 2) {
        int i = b * 256 + tid;
        if (i < NBUCK) bcursor[i] = 0;
        return;
    }
    b -= 2;
    const float* W;
    uint32* WT;
    int N;
    if (b < 32) { W = W1; WT = wt1; N = 128; }
    else if (b < 64) { W = W2; WT = wt2; N = 128; b -= 32; }
    else { W = W3; WT = wt3; N = 64; b -= 64; }
    int i = b * 256 + tid;
    if (i >= N * 64) return;
    int n = i >> 6, p = i & 63;
    WT[n * 64 + p] = f32_to_bf16_rne(W[(2 * p) * N + n]) |
                     (f32_to_bf16_rne(W[(2 * p + 1) * N + n]) << 16);
}

// ---------------- MFMA epilogue helper: pack bf16 col-pairs, store ----------------
__device__ __forceinline__ void pack_store(uint32* __restrict__ Cb, int rowstride_u,
                                           int row, int col, int r16, float v) {
    float nb = __shfl_xor(v, 1);
    if ((r16 & 1) == 0) {
        uint32 p = f32_to_bf16_rne(v) | (f32_to_bf16_rne(nb) << 16);
        Cb[(size_t)row * rowstride_u + (col >> 1)] = p;
    }
}

// ---------------- gemm1 body: A f32 global, converted in-register (64-row blocks) ----
__device__ __forceinline__ void gemm1_body(const float* __restrict__ A,
                                           const uint32* __restrict__ WTb,
                                           uint32* __restrict__ Cb, int M, int bid) {
    constexpr int NT = 2;
    const int tid = threadIdx.x;
    const int wave = tid >> 6;
    const int lane = tid & 63;
    const int r16 = lane & 15;
    const int g = lane >> 4;
    const int row0 = bid * 64;

    const float4* A4 = reinterpret_cast<const float4*>(A);
    const uint4* B4 = reinterpret_cast<const uint4*>(WTb);

    f32x4 acc[4][NT];
#pragma unroll
    for (int m = 0; m < 4; m++)
#pragma unroll
        for (int nt = 0; nt < NT; nt++) acc[m][nt] = (f32x4){0.f, 0.f, 0.f, 0.f};

    int rowm[4];
#pragma unroll
    for (int m = 0; m < 4; m++) {
        int r = row0 + m * 16 + r16;
        rowm[m] = r < M ? r : M - 1;
    }
    union U { uint4 u; bf16x8 v; };
#pragma unroll
    for (int kt = 0; kt < 4; kt++) {
        U b[NT];
#pragma unroll
        for (int nt = 0; nt < NT; nt++)
            b[nt].u = B4[(size_t)(nt * 64 + wave * 16 + r16) * 16 + kt * 4 + g];
        U a[4];
#pragma unroll
        for (int m = 0; m < 4; m++) {
            float4 f0 = A4[(size_t)rowm[m] * 32 + kt * 8 + g * 2];
            float4 f1 = A4[(size_t)rowm[m] * 32 + kt * 8 + g * 2 + 1];
            a[m].u.x = f32_to_bf16_rne(f0.x) | (f32_to_bf16_rne(f0.y) << 16);
            a[m].u.y = f32_to_bf16_rne(f0.z) | (f32_to_bf16_rne(f0.w) << 16);
            a[m].u.z = f32_to_bf16_rne(f1.x) | (f32_to_bf16_rne(f1.y) << 16);
            a[m].u.w = f32_to_bf16_rne(f1.z) | (f32_to_bf16_rne(f1.w) << 16);
        }
#pragma unroll
        for (int m = 0; m < 4; m++)
#pragma unroll
            for (int nt = 0; nt < NT; nt++)
                acc[m][nt] = __builtin_amdgcn_mfma_f32_16x16x32_bf16(a[m].v, b[nt].v, acc[m][nt], 0, 0, 0);
    }
#pragma unroll
    for (int m = 0; m < 4; m++)
#pragma unroll
        for (int nt = 0; nt < NT; nt++)
#pragma unroll
            for (int r = 0; r < 4; r++) {
                int row = row0 + m * 16 + g * 4 + r;
                if (row < M)
                    pack_store(Cb, 64, row, nt * 64 + wave * 16 + r16, r16, acc[m][nt][r]);
            }
}

// ---------------- fused edge-bucket scatter + gemm1 ----------------
#define GEMM1_BLOCKS 782     // ceil(50000/64)
#define SCAT_BLOCKS 391      // ceil(800000/2048)

__global__ __launch_bounds__(256) void scatter_gemm1_kernel(const float* __restrict__ x,
                                                            const uint32* __restrict__ wt1,
                                                            uint32* __restrict__ hwb,
                                                            const int* __restrict__ ei,
                                                            uint32* __restrict__ bcursor,
                                                            uint32* __restrict__ bedges) {
    if (blockIdx.x < GEMM1_BLOCKS) {
        gemm1_body(x, wt1, hwb, N_NODES, blockIdx.x);
        return;
    }
    const int chunk = blockIdx.x - GEMM1_BLOCKS;
    __shared__ uint32 hist[NBUCK];
    const int tid = threadIdx.x;
    for (int t = tid; t < NBUCK; t += 256) hist[t] = 0;
    __syncthreads();

    uint32 meta[8], payload[8];
    const int base = chunk * 2048;
#pragma unroll
    for (int k = 0; k < 8; k++) {
        int e = base + k * 256 + tid;
        meta[k] = 0xFFFFFFFFu;
        if (e < N_EDGES) {
            int s = ei[e];
            int dt = ei[N_EDGES + e];
            if ((unsigned)dt < (unsigned)N_NODES) {
                if ((unsigned)s >= (unsigned)N_NODES) s = 0;
                int b = dt >> 7;
                uint32 slot = atomicAdd(&hist[b], 1u);   // LDS atomic
                meta[k] = (uint32)b | (slot << 9);
                payload[k] = (uint32)s | ((uint32)(dt & 127) << 16);
            }
        }
    }
    __syncthreads();
    for (int t = tid; t < NBUCK; t += 256) {
        uint32 h = hist[t];
        uint32 g = h ? atomicAdd(&bcursor[t], h) : 0u;   // global, coalesced batch
        hist[t] = g;                                     // now holds global base
    }
    __syncthreads();
#pragma unroll
    for (int k = 0; k < 8; k++) {
        if (meta[k] != 0xFFFFFFFFu) {
            uint32 b = meta[k] & 511u;
            uint32 addr = hist[b] + (meta[k] >> 9);
            if (addr < BCAP) bedges[(size_t)b * BCAP + addr] = payload[k];
        }
    }
}

// ---------------- bucket -> adjacency rows (LDS cursors, zero global atomics) ----
__global__ __launch_bounds__(256) void bucket_build_kernel(const uint32* __restrict__ bedges,
                                                           const uint32* __restrict__ bcursor,
                                                           u16* __restrict__ adj,
                                                           int* __restrict__ deg) {
    const int b = blockIdx.x;
    __shared__ uint32 cur[128];
    const int tid = threadIdx.x;
    if (tid < 128) cur[tid] = 0;
    __syncthreads();
    uint32 cnt = bcursor[b];
    if (cnt > BCAP) cnt = BCAP;
    const uint32* be = bedges + (size_t)b * BCAP;
    for (uint32 i = tid; i < cnt; i += 256) {
        uint32 p = be[i];
        uint32 dl = p >> 16;
        uint32 s = p & 0xFFFFu;
        uint32 pos = atomicAdd(&cur[dl], 1u);            // LDS atomic
        if (pos < CAP) adj[((size_t)(b * 128 + dl)) * CAP + pos] = (u16)s;
    }
    __syncthreads();
    if (tid < 128) {
        int n = b * 128 + tid;
        if (n < N_NODES) deg[n] = (int)cur[tid];
    }
}

__device__ __forceinline__ void acc8(float a[8], const uint4& v) {
    a[0] += bf16lo_to_f32(v.x); a[1] += bf16hi_to_f32(v.x);
    a[2] += bf16lo_to_f32(v.y); a[3] += bf16hi_to_f32(v.y);
    a[4] += bf16lo_to_f32(v.z); a[5] += bf16hi_to_f32(v.z);
    a[6] += bf16lo_to_f32(v.w); a[7] += bf16hi_to_f32(v.w);
}

// ---------------- fused aggregate(layer l) + gemm(layer l+1 messages) ----------------
// Block: 16 nodes (grid 3125). Wave gathers its FOUR nodes INTERLEAVED:
// per iteration, 8 uint4 loads (2 per node x 4 nodes) are issued before any
// consumption -> 128 B/lane in flight; small-degree remainders overlap.
template <int N>
__global__ __launch_bounds__(256) void agg_gemm_kernel(const uint32* __restrict__ hw_in,
                                                       const u16* __restrict__ adj,
                                                       const int* __restrict__ deg,
                                                       const float* __restrict__ bias,
                                                       float* __restrict__ o_out,
                                                       const uint32* __restrict__ WTb,
                                                       uint32* __restrict__ hw_out) {
    constexpr int TPW = N / 64;
    constexpr int LDR = 68;
    __shared__ uint32 Asm[16 * LDR];

    const int tid = threadIdx.x;
    const int wave = tid >> 6;
    const int lane = tid & 63;
    const int f = lane & 15;
    const int j = lane >> 4;  // edge sub-slot 0..3
    const int base = blockIdx.x * 16;
    const uint32* sbase = hw_in + f * 4;

    int dd[4], slot[4];
#pragma unroll
    for (int i = 0; i < 4; i++) {
        int n = base + wave * 4 + i;
        int d = __builtin_amdgcn_readfirstlane(deg[n]);
        dd[i] = d > CAP ? CAP : d;
        slot[i] = adj[n * CAP + lane];
    }
    int dmax = dd[0];
#pragma unroll
    for (int i = 1; i < 4; i++) dmax = dd[i] > dmax ? dd[i] : dmax;

    float a[4][8];
#pragma unroll
    for (int i = 0; i < 4; i++)
#pragma unroll
        for (int k = 0; k < 8; k++) a[i][k] = 0.f;

    for (int e = 0; e < dmax; e += 8) {
        uint4 v0[4], v1[4];
#pragma unroll
        for (int i = 0; i < 4; i++) {
            int i0 = e + j;
            int i1 = e + 4 + j;
            int s0 = __shfl(slot[i], i0 < dd[i] ? i0 : 0);
            int s1 = __shfl(slot[i], i1 < dd[i] ? i1 : 0);
            v0[i] = make_uint4(0u, 0u, 0u, 0u);
            v1[i] = make_uint4(0u, 0u, 0u, 0u);
            if (i0 < dd[i]) v0[i] = *reinterpret_cast<const uint4*>(sbase + (size_t)s0 * 64);
            if (i1 < dd[i]) v1[i] = *reinterpret_cast<const uint4*>(sbase + (size_t)s1 * 64);
        }
#pragma unroll
        for (int i = 0; i < 4; i++) {
            acc8(a[i], v0[i]);
            acc8(a[i], v1[i]);
        }
    }

#pragma unroll
    for (int i = 0; i < 4; i++) {
#pragma unroll
        for (int off = 16; off < 64; off <<= 1)
#pragma unroll
            for (int k = 0; k < 8; k++) a[i][k] += __shfl_xor(a[i][k], off);
        if (lane < 16) {
            int n = base + wave * 4 + i;
            float4 b0 = *reinterpret_cast<const float4*>(&bias[f * 8]);
            float4 b1 = *reinterpret_cast<const float4*>(&bias[f * 8 + 4]);
            a[i][0] += b0.x; a[i][1] += b0.y; a[i][2] += b0.z; a[i][3] += b0.w;
            a[i][4] += b1.x; a[i][5] += b1.y; a[i][6] += b1.z; a[i][7] += b1.w;
            *reinterpret_cast<float4*>(&o_out[(size_t)n * 128 + f * 8]) =
                make_float4(a[i][0], a[i][1], a[i][2], a[i][3]);
            *reinterpret_cast<float4*>(&o_out[(size_t)n * 128 + f * 8 + 4]) =
                make_float4(a[i][4], a[i][5], a[i][6], a[i][7]);
            uint4 p;
            p.x = f32_to_bf16_rne(a[i][0]) | (f32_to_bf16_rne(a[i][1]) << 16);
            p.y = f32_to_bf16_rne(a[i][2]) | (f32_to_bf16_rne(a[i][3]) << 16);
            p.z = f32_to_bf16_rne(a[i][4]) | (f32_to_bf16_rne(a[i][5]) << 16);
            p.w = f32_to_bf16_rne(a[i][6]) | (f32_to_bf16_rne(a[i][7]) << 16);
            *reinterpret_cast<uint4*>(&Asm[(wave * 4 + i) * LDR + f * 4]) = p;
        }
    }
    __syncthreads();

    const int r16 = lane & 15;
    const int g = lane >> 4;
    const uint4* B4 = reinterpret_cast<const uint4*>(WTb);

    f32x4 acc[TPW];
#pragma unroll
    for (int nt = 0; nt < TPW; nt++) acc[nt] = (f32x4){0.f, 0.f, 0.f, 0.f};

    union U { uint4 u; bf16x8 v; };
#pragma unroll
    for (int kt = 0; kt < 4; kt++) {
        U av;
        av.u = *reinterpret_cast<const uint4*>(&Asm[r16 * LDR + (kt * 4 + g) * 4]);
        U b[TPW];
#pragma unroll
        for (int nt = 0; nt < TPW; nt++) {
            int col = (wave * TPW + nt) * 16 + r16;
            b[nt].u = B4[(size_t)col * 16 + kt * 4 + g];
        }
#pragma unroll
        for (int nt = 0; nt < TPW; nt++)
            acc[nt] = __builtin_amdgcn_mfma_f32_16x16x32_bf16(av.v, b[nt].v, acc[nt], 0, 0, 0);
    }
#pragma unroll
    for (int nt = 0; nt < TPW; nt++)
#pragma unroll
        for (int r = 0; r < 4; r++) {
            int row = base + g * 4 + r;
            pack_store(hw_out, N / 2, row, (wave * TPW + nt) * 16 + r16, r16, acc[nt][r]);
        }
}

// ---------------- final aggregate F=64: 1 node/wave, uint4 gather (8 lanes/row) ----
__global__ __launch_bounds__(256) void aggregate64_kernel(const uint32* __restrict__ hwb,
                                                          const u16* __restrict__ adj,
                                                          const int* __restrict__ deg,
                                                          const float* __restrict__ bias,
                                                          float* __restrict__ out) {
    int n = (blockIdx.x * blockDim.x + threadIdx.x) >> 6;
    if (n >= N_NODES) return;
    const int lane = threadIdx.x & 63;
    const int f = lane & 7;
    const int j = lane >> 3;
    int d = __builtin_amdgcn_readfirstlane(deg[n]);
    if (d > CAP) d = CAP;
    int myslot = adj[n * CAP + lane];
    const uint32* sbase = hwb + f * 4;

    float a[8] = {0.f, 0.f, 0.f, 0.f, 0.f, 0.f, 0.f, 0.f};
    int e = 0;
    for (; e + 16 <= d; e += 16) {
        int s0 = __shfl(myslot, e + j);
        int s1 = __shfl(myslot, e + 8 + j);
        uint4 v0 = *reinterpret_cast<const uint4*>(sbase + (size_t)s0 * 32);
        uint4 v1 = *reinterpret_cast<const uint4*>(sbase + (size_t)s1 * 32);
        acc8(a, v0);
        acc8(a, v1);
    }
    for (; e < d; e += 8) {
        int idx = e + j;
        int s = __shfl(myslot, idx < d ? idx : e);
        uint4 v = make_uint4(0u, 0u, 0u, 0u);
        if (idx < d) v = *reinterpret_cast<const uint4*>(sbase + (size_t)s * 32);
        acc8(a, v);
    }
#pragma unroll
    for (int off = 8; off < 64; off <<= 1)
#pragma unroll
        for (int k = 0; k < 8; k++) a[k] += __shfl_xor(a[k], off);
    if (lane < 8) {
        float4 b0 = *reinterpret_cast<const float4*>(&bias[f * 8]);
        float4 b1 = *reinterpret_cast<const float4*>(&bias[f * 8 + 4]);
        *reinterpret_cast<float4*>(&out[(size_t)n * 64 + f * 8]) =
            make_float4(a[0] + b0.x, a[1] + b0.y, a[2] + b0.z, a[3] + b0.w);
        *reinterpret_cast<float4*>(&out[(size_t)n * 64 + f * 8 + 4]) =
            make_float4(a[4] + b1.x, a[5] + b1.y, a[6] + b1.z, a[7] + b1.w);
    }
}

extern "C" void kernel_launch(void* const* d_in, const int* in_sizes, int n_in,
                              void* d_out, int out_size, void* d_ws, size_t ws_size,
                              hipStream_t stream) {
    const float* x  = (const float*)d_in[0];
    const int*   ei = (const int*)d_in[1];
    const float* W1 = (const float*)d_in[2];
    const float* b1 = (const float*)d_in[3];
    const float* W2 = (const float*)d_in[4];
    const float* b2 = (const float*)d_in[5];
    const float* W3 = (const float*)d_in[6];
    const float* b3 = (const float*)d_in[7];

    float* o1 = (float*)d_out;
    float* o2 = o1 + (size_t)N_NODES * 128;
    float* o3 = o2 + (size_t)N_NODES * 128;

    char* ws = (char*)d_ws;
    uint32* hwbA    = (uint32*)(ws);                 // 12.8 MB
    uint32* hwbB    = (uint32*)(ws + 12800000);      // 12.8 MB
    u16*    adj     = (u16*)(ws + 25600000);         // 6.4 MB
    int*    deg     = (int*)(ws + 32000000);         // 200 KB
    uint32* bedges  = (uint32*)(ws + 32200000);      // 391*3072*4 = 4.8 MB
    uint32* bcursor = (uint32*)(ws + 37004608);      // 1.6 KB
    uint32* wt1     = (uint32*)(ws + 37006464);      // 32 KB
    uint32* wt2     = (uint32*)(ws + 37039232);      // 32 KB
    uint32* wt3     = (uint32*)(ws + 37072000);      // 16 KB

    // 1. prep: zero bucket cursors + WT tables
    prep_kernel<<<82, 256, 0, stream>>>(W1, W2, W3, wt1, wt2, wt3, bcursor);
    // 2. fused edge-bucket scatter + gemm1 (x@W1 -> hwbA)
    scatter_gemm1_kernel<<<GEMM1_BLOCKS + SCAT_BLOCKS, 256, 0, stream>>>(x, wt1, hwbA, ei, bcursor, bedges);
    // 3. bucket -> adjacency rows + deg (LDS cursors only)
    bucket_build_kernel<<<NBUCK, 256, 0, stream>>>(bedges, bcursor, adj, deg);
    // 4. agg1 (+b1 -> o1) fused with gemm2 -> hwbB
    agg_gemm_kernel<128><<<3125, 256, 0, stream>>>(hwbA, adj, deg, b1, o1, wt2, hwbB);
    // 5. agg2 (+b2 -> o2) fused with gemm3 -> hwbA
    agg_gemm_kernel<64><<<3125, 256, 0, stream>>>(hwbB, adj, deg, b2, o2, wt3, hwbA);
    // 6. agg3 (+b3 -> o3)
    aggregate64_kernel<<<12500, 256, 0, stream>>>(hwbA, adj, deg, b3, o3);
}